// Round 7
// baseline (110.922 us; speedup 1.0000x reference)
//
#include <hip/hip_runtime.h>
#include <math.h>

#define Bb 2
#define Nn 2048
#define Hh 256
#define NH 8
#define HD 32
#define NEDGE 65536
#define LN_EPS 1e-5f
#define MW 64          // mask words per row = N/32
#define LDA2 72
#define ALD 264        // As row stride (bf16)
#define NBW 2112       // nbr row stride: 2048 + 3 sentinels, padded

typedef __bf16 bf16_t;
typedef bf16_t bf16x8 __attribute__((ext_vector_type(8)));
typedef bf16_t bf16x4 __attribute__((ext_vector_type(4)));
typedef float f32x4 __attribute__((ext_vector_type(4)));

// ===========================================================================
// K0: QKV GEMM (units 0..767) + build mask from edges (units 768..1023).
// Mask zeroed by hipMemsetAsync before this kernel (stream-ordered).
// ===========================================================================
__global__ __launch_bounds__(256) void prep_kernel(
    const float* __restrict__ x,
    const float* __restrict__ Wq, const float* __restrict__ Wk, const float* __restrict__ Wv,
    const int* __restrict__ ei,
    float* __restrict__ Qb, bf16_t* __restrict__ Kb16, bf16_t* __restrict__ Vb16,
    unsigned int* __restrict__ mask)
{
    __shared__ bf16_t As[64 * LDA2];
    __shared__ bf16_t Ws[64 * LDA2];
    const int u = blockIdx.x;
    const int t = threadIdx.x;

    if (u >= 768) {
        int e = (u - 768) * 256 + t;
        int src = ei[e];
        int dst = ei[NEDGE + e];
        atomicOr(&mask[src * MW + (dst >> 5)], 1u << (dst & 31));
        return;
    }

    const int lane = t & 63, w = t >> 6;
    const int wm = w & 1, wn = w >> 1;
    const int ml = lane & 15, quad = lane >> 4;
    const int m0 = (u & 63) << 6;
    const int ysel = u >> 6;
    const int wsel = ysel >> 2;
    const float* W = (wsel == 0) ? Wq : ((wsel == 1) ? Wk : Wv);
    const int n0 = (ysel & 3) << 6;
    const int srow = t >> 3, scol = (t & 7) * 8;
    f32x4 acc[2][2];
    f32x4 zero = {0.f, 0.f, 0.f, 0.f};
    acc[0][0] = zero; acc[0][1] = zero; acc[1][0] = zero; acc[1][1] = zero;

    for (int k0 = 0; k0 < Hh; k0 += 64) {
        float4 a[2][2], bwt[2][2];
        #pragma unroll
        for (int s = 0; s < 2; ++s) {
            const float* ap = x + (size_t)(m0 + srow + s * 32) * Hh + k0 + scol;
            a[s][0] = *(const float4*)ap;
            a[s][1] = *(const float4*)(ap + 4);
            const float* bp = W + (size_t)(n0 + srow + s * 32) * Hh + k0 + scol;
            bwt[s][0] = *(const float4*)bp;
            bwt[s][1] = *(const float4*)(bp + 4);
        }
        __syncthreads();
        #pragma unroll
        for (int s = 0; s < 2; ++s) {
            bf16x8 av = {(bf16_t)a[s][0].x, (bf16_t)a[s][0].y, (bf16_t)a[s][0].z, (bf16_t)a[s][0].w,
                         (bf16_t)a[s][1].x, (bf16_t)a[s][1].y, (bf16_t)a[s][1].z, (bf16_t)a[s][1].w};
            bf16x8 bv = {(bf16_t)bwt[s][0].x, (bf16_t)bwt[s][0].y, (bf16_t)bwt[s][0].z, (bf16_t)bwt[s][0].w,
                         (bf16_t)bwt[s][1].x, (bf16_t)bwt[s][1].y, (bf16_t)bwt[s][1].z, (bf16_t)bwt[s][1].w};
            *(bf16x8*)&As[(srow + s * 32) * LDA2 + scol] = av;
            *(bf16x8*)&Ws[(srow + s * 32) * LDA2 + scol] = bv;
        }
        __syncthreads();
        #pragma unroll
        for (int kk = 0; kk < 64; kk += 32) {
            bf16x8 af[2], bfr[2];
            #pragma unroll
            for (int i = 0; i < 2; ++i) {
                af[i]  = *(const bf16x8*)&As[(wm * 32 + i * 16 + ml) * LDA2 + kk + quad * 8];
                bfr[i] = *(const bf16x8*)&Ws[(wn * 32 + i * 16 + ml) * LDA2 + kk + quad * 8];
            }
            #pragma unroll
            for (int i = 0; i < 2; ++i)
                #pragma unroll
                for (int j = 0; j < 2; ++j)
                    acc[i][j] = __builtin_amdgcn_mfma_f32_16x16x32_bf16(af[i], bfr[j], acc[i][j], 0, 0, 0);
        }
    }
    bf16_t* Ob16 = (wsel == 1) ? Kb16 : Vb16;
    #pragma unroll
    for (int i = 0; i < 2; ++i)
        #pragma unroll
        for (int j = 0; j < 2; ++j)
            #pragma unroll
            for (int r = 0; r < 4; ++r) {
                int mg = m0 + wm * 32 + i * 16 + quad * 4 + r;
                int ng = n0 + wn * 32 + j * 16 + ml;
                float v = acc[i][j][r];
                if (wsel == 0) Qb[(size_t)mg * Hh + ng] = v;
                else           Ob16[(size_t)mg * Hh + ng] = (bf16_t)v;
            }
}

// ===========================================================================
// K1: fused attention + out-projection + residual + LayerNorm (v2).
// Block = 512 threads = 8 waves, 8 rows/block, grid 512 -> 2 blocks/CU
// co-resident (38 KB LDS). Wave w owns global row g = bid*8 + w and runs the
// in-register online-softmax split into EVEN/ODD independent chains (2x ILP
// on the serial exp/fma chain; prefetch distance 2), merged once at the end.
// Epilogue: M=8 A-tile in LDS (rows 8..15 fed as zeros), B-fragments loaded
// DIRECTLY from fp32 Wo (in-register bf16 cvt, same RNE rounding + k-order
// as before -> bit-identical out-proj). Only 3 block barriers total.
// ===========================================================================
__global__ __launch_bounds__(512, 4) void attn_fused2_kernel(
    const float* __restrict__ Qb, const bf16_t* __restrict__ Kb16, const bf16_t* __restrict__ Vb16,
    const unsigned int* __restrict__ mask, const float* __restrict__ Wo,
    const float* __restrict__ x, const float* __restrict__ gamma, const float* __restrict__ beta,
    float* __restrict__ out)
{
    __shared__ __align__(16) char smem[8 * NBW * 2 + 8 * ALD * 2];   // 38016 B
    unsigned short* nbr = (unsigned short*)smem;            // [8][NBW]
    float*  ybuf = (float*)smem;                            // [8][260] fp32, alias over nbr
    bf16_t* As   = (bf16_t*)(smem + 8 * NBW * 2);           // [8][ALD]

    const int t = threadIdx.x;
    const int w = t >> 6, lane = t & 63;
    const int ml = lane & 15, quad = lane >> 4;
    const int g = (blockIdx.x << 3) + w;     // global row 0..4095
    const int i = g & (Nn - 1);
    const int b = g >> 11;

    // ---- decode mask row i into this wave's neighbor list ----
    unsigned int bits = mask[i * MW + lane];
    int cnt = __popc(bits);
    int incl = cnt;
    #pragma unroll
    for (int off = 1; off < 64; off <<= 1) {
        int v = __shfl_up(incl, off, 64);
        if (lane >= off) incl += v;
    }
    int idx = incl - cnt;
    unsigned int bb = bits;
    while (bb) {
        int bit = __ffs(bb) - 1;
        nbr[w * NBW + idx++] = (unsigned short)(lane * 32 + bit);
        bb &= bb - 1;
    }
    int nn = __shfl(incl, 63, 64);
    if (lane == 63) {   // 3 sentinels keep pair-prefetch addresses valid
        nbr[w * NBW + idx]     = 0;
        nbr[w * NBW + idx + 1] = 0;
        nbr[w * NBW + idx + 2] = 0;
    }
    __syncthreads();

    // ---- even/odd dual-chain online-softmax attention ----
    const int off4 = lane << 2;
    const float4 qv = *(const float4*)(Qb + (size_t)g * Hh + off4);
    const bf16_t* kb = Kb16 + ((size_t)b << 19);   // b * 2048 * 256
    const bf16_t* vb = Vb16 + ((size_t)b << 19);
    const float scale = 0.17677669529663687f;      // 1/sqrt(32)

    float m_e = -1e30f, l_e = 0.f, e0 = 0.f, e1 = 0.f, e2 = 0.f, e3 = 0.f;
    float m_o = -1e30f, l_o = 0.f, d0 = 0.f, d1 = 0.f, d2 = 0.f, d3 = 0.f;
    if (nn > 0) {
        const unsigned short* nb = &nbr[w * NBW];
        int j0 = nb[0], j1 = nb[1];
        bf16x4 kve = *(const bf16x4*)(kb + ((size_t)j0 << 8) + off4);
        bf16x4 vve = *(const bf16x4*)(vb + ((size_t)j0 << 8) + off4);
        bf16x4 kvo = *(const bf16x4*)(kb + ((size_t)j1 << 8) + off4);
        bf16x4 vvo = *(const bf16x4*)(vb + ((size_t)j1 << 8) + off4);
        for (int n = 0; n < nn; n += 2) {
            int j2 = nb[n + 2], j3 = nb[n + 3];    // sentinel-safe
            bf16x4 kne = *(const bf16x4*)(kb + ((size_t)j2 << 8) + off4);
            bf16x4 vne = *(const bf16x4*)(vb + ((size_t)j2 << 8) + off4);
            bf16x4 kno = *(const bf16x4*)(kb + ((size_t)j3 << 8) + off4);
            bf16x4 vno = *(const bf16x4*)(vb + ((size_t)j3 << 8) + off4);
            // even chain: neighbor n
            {
                float p = fmaf((float)kve.x, qv.x, fmaf((float)kve.y, qv.y,
                          fmaf((float)kve.z, qv.z, (float)kve.w * qv.w)));
                p += __shfl_xor(p, 1, 64);
                p += __shfl_xor(p, 2, 64);
                p += __shfl_xor(p, 4, 64);
                p *= scale;
                float mn = fmaxf(m_e, p);
                float al = __expf(m_e - mn);
                float wg = __expf(p - mn);
                l_e = fmaf(l_e, al, wg);
                e0 = fmaf(e0, al, wg * (float)vve.x);
                e1 = fmaf(e1, al, wg * (float)vve.y);
                e2 = fmaf(e2, al, wg * (float)vve.z);
                e3 = fmaf(e3, al, wg * (float)vve.w);
                m_e = mn;
            }
            // odd chain: neighbor n+1 (wave-uniform guard: nn uniform per wave)
            if (n + 1 < nn) {
                float p = fmaf((float)kvo.x, qv.x, fmaf((float)kvo.y, qv.y,
                          fmaf((float)kvo.z, qv.z, (float)kvo.w * qv.w)));
                p += __shfl_xor(p, 1, 64);
                p += __shfl_xor(p, 2, 64);
                p += __shfl_xor(p, 4, 64);
                p *= scale;
                float mn = fmaxf(m_o, p);
                float al = __expf(m_o - mn);
                float wg = __expf(p - mn);
                l_o = fmaf(l_o, al, wg);
                d0 = fmaf(d0, al, wg * (float)vvo.x);
                d1 = fmaf(d1, al, wg * (float)vvo.y);
                d2 = fmaf(d2, al, wg * (float)vvo.z);
                d3 = fmaf(d3, al, wg * (float)vvo.w);
                m_o = mn;
            }
            kve = kne; vve = vne; kvo = kno; vvo = vno;
        }
    }
    // merge the two chains (flash-style state merge)
    float mm = fmaxf(m_e, m_o);
    float se = __expf(m_e - mm);     // 0 if chain empty (exp(-inf))
    float so = __expf(m_o - mm);
    float l  = fmaf(l_e, se, l_o * so);
    float o0 = fmaf(e0, se, d0 * so);
    float o1 = fmaf(e1, se, d1 * so);
    float o2 = fmaf(e2, se, d2 * so);
    float o3 = fmaf(e3, se, d3 * so);
    float linv = (l > 0.f) ? 1.f / l : 0.f;
    bf16x4 arow = {(bf16_t)(o0 * linv), (bf16_t)(o1 * linv),
                   (bf16_t)(o2 * linv), (bf16_t)(o3 * linv)};
    *(bf16x4*)&As[w * ALD + off4] = arow;
    __syncthreads();   // all 8 A-rows written; all nbr reads complete

    // ---- out-projection: C[8 x 256] = A @ Wo^T; wave w -> cols w*32..w*32+31.
    // B-fragments straight from fp32 Wo (no LDS staging, no barriers).
    f32x4 acc[2];
    {
        f32x4 pz = {0.f, 0.f, 0.f, 0.f};
        acc[0] = pz; acc[1] = pz;
    }
    const bf16x8 zero8 = {(bf16_t)0.f, (bf16_t)0.f, (bf16_t)0.f, (bf16_t)0.f,
                          (bf16_t)0.f, (bf16_t)0.f, (bf16_t)0.f, (bf16_t)0.f};
    #pragma unroll
    for (int k8 = 0; k8 < 8; ++k8) {       // k ascending, 32-wide -> same order
        bf16x8 af = zero8;
        if (ml < 8) af = *(const bf16x8*)&As[ml * ALD + (k8 << 5) + (quad << 3)];
        #pragma unroll
        for (int ct = 0; ct < 2; ++ct) {
            const float* wp = Wo + (size_t)((w << 5) + (ct << 4) + ml) * Hh + (k8 << 5) + (quad << 3);
            float4 w0 = ((const float4*)wp)[0];
            float4 w1 = ((const float4*)wp)[1];
            bf16x8 bfr = {(bf16_t)w0.x, (bf16_t)w0.y, (bf16_t)w0.z, (bf16_t)w0.w,
                          (bf16_t)w1.x, (bf16_t)w1.y, (bf16_t)w1.z, (bf16_t)w1.w};
            acc[ct] = __builtin_amdgcn_mfma_f32_16x16x32_bf16(af, bfr, acc[ct], 0, 0, 0);
        }
    }
    // ---- residual into ybuf (aliases nbr; safe after the As barrier) ----
    if (quad < 2) {
        #pragma unroll
        for (int ct = 0; ct < 2; ++ct)
            #pragma unroll
            for (int r = 0; r < 4; ++r) {
                int row = quad * 4 + r;                    // 0..7
                int col = (w << 5) + (ct << 4) + ml;
                ybuf[row * 260 + col] = acc[ct][r] + x[(size_t)((blockIdx.x << 3) + row) * Hh + col];
            }
    }
    __syncthreads();
    // ---- LayerNorm: wave w handles row w ----
    {
        float4 v = *(const float4*)&ybuf[w * 260 + off4];
        float sum = v.x + v.y + v.z + v.w;
        #pragma unroll
        for (int m = 1; m < 64; m <<= 1) sum += __shfl_xor(sum, m, 64);
        float mu = sum * (1.f / Hh);
        float4 d = {v.x - mu, v.y - mu, v.z - mu, v.w - mu};
        float ss = d.x * d.x + d.y * d.y + d.z * d.z + d.w * d.w;
        #pragma unroll
        for (int m = 1; m < 64; m <<= 1) ss += __shfl_xor(ss, m, 64);
        float r = rsqrtf(ss * (1.f / Hh) + LN_EPS);
        float4 gm = *(const float4*)(gamma + off4);
        float4 bt = *(const float4*)(beta + off4);
        float4 ov = {d.x * r * gm.x + bt.x, d.y * r * gm.y + bt.y,
                     d.z * r * gm.z + bt.z, d.w * r * gm.w + bt.w};
        *(float4*)(out + (size_t)g * Hh + off4) = ov;
    }
}

extern "C" void kernel_launch(void* const* d_in, const int* in_sizes, int n_in,
                              void* d_out, int out_size, void* d_ws, size_t ws_size,
                              hipStream_t stream) {
    const float* x     = (const float*)d_in[0];
    const int*   ei    = (const int*)d_in[1];
    // d_in[2] = edge_weights: unused by the reference
    const float* Wq    = (const float*)d_in[3];
    const float* Wk    = (const float*)d_in[4];
    const float* Wv    = (const float*)d_in[5];
    const float* Wo    = (const float*)d_in[6];
    const float* gamma = (const float*)d_in[7];
    const float* beta  = (const float*)d_in[8];
    float* out = (float*)d_out;

    const int NTOK = Bb * Nn * Hh;  // 1048576
    float*  Qb    = (float*)d_ws;
    bf16_t* Kb16  = (bf16_t*)(Qb + NTOK);
    bf16_t* Vb16  = Kb16 + NTOK;
    unsigned int* mask = (unsigned int*)(Vb16 + NTOK);

    hipMemsetAsync(mask, 0, Nn * MW * sizeof(unsigned int), stream);
    hipLaunchKernelGGL(prep_kernel, dim3(1024), dim3(256), 0, stream,
                       x, Wq, Wk, Wv, ei, Qb, Kb16, Vb16, mask);
    hipLaunchKernelGGL(attn_fused2_kernel, dim3((Bb * Nn) / 8), dim3(512), 0, stream,
                       Qb, Kb16, Vb16, mask, Wo, x, gamma, beta, out);
}